// Round 6
// baseline (136.081 us; speedup 1.0000x reference)
//
#include <hip/hip_runtime.h>
#include <math.h>

#define G 128
#define NCELLS (G*G)            // 16384
#define RAD 20
#define NS 41
#define NTAPS (NS*NS)           // 1681
#define NB_FULL 1850.0f         // 1 + (2R+3)^2 entries in the mean
#define NTAIL 168.0f            // (2R+3)^2 - (2R+1)^2
#define NRULES 4
#define NQ 16                   // stencil-row slices
#define QROWPAD 44
#define QBLK 144                // per-block stencil scratch stride (floats, 16B-aligned)
#define NTILES 16               // 8-row tiles
#define CONV_BLOCKS (NTILES*NRULES*NQ)   // 1024

// ws layout (float offsets); ws is 256 MiB so space is not a constraint
#define WOFF_TAIL 0                                 // 4 floats (pad to 16)
#define WOFF_POT  16                                // 64 * NCELLS partial potentials
#define WOFF_BW   (WOFF_POT + NRULES*NQ*NCELLS)     // 1024 * 144 per-block stencil slices

__device__ __forceinline__ float kw(float d, float irk,
                                    float rk0, float rk1, float rk2,
                                    float b0, float b1, float b2,
                                    float iw0, float iw1, float iw2) {
    float em = 1.f / (1.f + __expf((d - 1.f) * 10.f));
    float dd = d * irk;
    float u0 = (dd - rk0) * iw0;
    float u1 = (dd - rk1) * iw1;
    float u2 = (dd - rk2) * iw2;
    return em * (b0 * __expf(-0.5f * u0 * u0)
               + b1 * __expf(-0.5f * u1 * u1)
               + b2 * __expf(-0.5f * u2 * u2));
}

// 1024 blocks: (16 eight-row tiles) x (4 rules) x (16 stencil-row slices).
// 256 threads = 8 rows x 32 lanes; 4 adjacent cells per thread.
__global__ __launch_bounds__(256, 4)
void lenia_conv(const float* __restrict__ x,
                const int* __restrict__ c0v,
                const float* __restrict__ rr,
                const float* __restrict__ rkv,
                const float* __restrict__ bv,
                const float* __restrict__ wv,
                float* __restrict__ ws) {
    __shared__ __align__(16) float xt[10*168];   // <= 10 halo'd rows
    __shared__ float red[4];

    const int bid  = blockIdx.x;
    const int q    = bid & 15;
    const int k    = (bid >> 4) & 3;
    const int tile = bid >> 6;                   // 0..15
    const int i0   = tile * 8;
    const int t    = threadIdx.x;
    // slices: nine rows-of-3 then seven rows-of-2 (9*3 + 7*2 = 41)
    const int nsi  = (q < 9) ? 3 : 2;
    const int si0  = (q < 9) ? 3*q : 27 + 2*(q - 9);
    const int r0   = i0 - RAD + si0;
    const int NR   = nsi + 7;                    // staged rows (<=10)
    const int ck   = c0v[k];                     // wave-uniform

    // ---- stage halo'd channel tile straight from interleaved x ----
    for (int idx = t; idx < NR * 168; idx += 256) {
        int rrow = idx / 168;
        int cc   = idx - rrow * 168;
        int grow = (r0 + rrow) & (G - 1);
        int gcol = (cc - 20) & (G - 1);
        xt[rrow*168 + cc] = x[grow*(G*3) + gcol*3 + ck];
    }

    // ---- per-block stencil recompute (proven exact in R3/R4) ----
    const float irk = 1.f / rr[k];
    const float rk0 = rkv[k*3+0], rk1 = rkv[k*3+1], rk2 = rkv[k*3+2];
    const float b0  = bv[k*3+0],  b1  = bv[k*3+1],  b2  = bv[k*3+2];
    const float iw0 = 1.f / wv[k*3+0], iw1 = 1.f / wv[k*3+1], iw2 = 1.f / wv[k*3+2];
    const float invR = 1.f / (float)RAD;

    float vals[7];
    float lsum = 0.f;
    #pragma unroll
    for (int j = 0; j < 7; ++j) {
        int sidx = t + j * 256;
        float wk = 0.f;
        if (sidx < NTAPS) {
            int si = sidx / NS - RAD;
            int sj = sidx % NS - RAD;
            float d = sqrtf((float)(si*si + sj*sj)) * invR;
            wk = kw(d, irk, rk0, rk1, rk2, b0, b1, b2, iw0, iw1, iw2);
        }
        vals[j] = wk;
        lsum += wk;
    }
    #pragma unroll
    for (int mm = 32; mm > 0; mm >>= 1) lsum += __shfl_xor(lsum, mm, 64);
    if ((t & 63) == 0) red[t >> 6] = lsum;
    __syncthreads();                              // red ready AND xt staged
    const float S4 = red[0] + red[1] + red[2] + red[3];
    const float wself = kw(0.f, irk, rk0, rk1, rk2, b0, b1, b2, iw0, iw1, iw2);
    const float dtail = sqrtf(8192.f) * invR;
    const float wtail = kw(dtail, irk, rk0, rk1, rk2, b0, b1, b2, iw0, iw1, iw2);
    const float S = S4 + wself + NTAIL * wtail;
    const float inv = 1.f / (S * NB_FULL);

    // write this block's stencil slice to private global scratch (L1-hot on readback)
    float* bw = ws + WOFF_BW + bid * QBLK;
    const int lo = si0 * NS, hi = (si0 + nsi) * NS;
    #pragma unroll
    for (int j = 0; j < 7; ++j) {
        int sidx = t + j * 256;
        if (sidx >= lo && sidx < hi) {
            float v = vals[j] * inv;
            if (sidx == RAD*NS + RAD) v += wself * inv;   // fold self slot into (0,0)
            int l = sidx - lo;
            bw[(l / NS) * QROWPAD + (l % NS)] = v;
        }
    }
    if (t < 9) bw[(t / 3) * QROWPAD + NS + (t % 3)] = 0.f;   // zero pad cols rows 0..2
    if (tile == 0 && q == 0 && t == 0) ws[WOFF_TAIL + k] = NTAIL * wtail * inv;
    __syncthreads();                              // drains vmcnt: bw visible block-wide

    // ---- conv: 8 rows x 32 lanes, 4 adjacent cells per thread ----
    const int row = t >> 5;
    const int cb  = (t & 31) * 4;
    float a0 = 0.f, a1 = 0.f, a2 = 0.f, a3 = 0.f;

    for (int ii = 0; ii < nsi; ++ii) {
        const float* rp = &xt[(row + ii)*168 + cb];   // 16B-aligned
        float wwin[44];
        #pragma unroll
        for (int u = 0; u < 11; ++u) {
            float4 v = *(const float4*)&rp[4*u];
            wwin[4*u] = v.x; wwin[4*u+1] = v.y; wwin[4*u+2] = v.z; wwin[4*u+3] = v.w;
        }
        const float* wr = bw + ii * QROWPAD;          // wave-uniform address
        float wrow[44];
        #pragma unroll
        for (int u = 0; u < 11; ++u) {
            float4 v = *(const float4*)&wr[4*u];
            wrow[4*u] = v.x; wrow[4*u+1] = v.y; wrow[4*u+2] = v.z; wrow[4*u+3] = v.w;
        }
        #pragma unroll
        for (int s2 = 0; s2 < 41; ++s2) {
            a0 = fmaf(wrow[s2], wwin[s2],   a0);
            a1 = fmaf(wrow[s2], wwin[s2+1], a1);
            a2 = fmaf(wrow[s2], wwin[s2+2], a2);
            a3 = fmaf(wrow[s2], wwin[s2+3], a3);
        }
    }

    int cell = (i0 + row) * G + cb;
    float4 res; res.x = a0; res.y = a1; res.z = a2; res.w = a3;
    *(float4*)&ws[WOFF_POT + (k * NQ + q) * NCELLS + cell] = res;
}

// 256 blocks x 64: sum 64 partials, growth, delta, clip, pos pass-through.
__global__ __launch_bounds__(64)
void lenia_update(const float* __restrict__ pos,
                  const float* __restrict__ x,
                  const int* __restrict__ c0v,
                  const int* __restrict__ c1v,
                  const float* __restrict__ hv,
                  const float* __restrict__ mv,
                  const float* __restrict__ sv,
                  const float* __restrict__ ws,
                  float* __restrict__ out) {
    int n = blockIdx.x * 64 + threadIdx.x;
    *(float2*)&out[2*n] = *(const float2*)&pos[2*n];

    float xv0 = x[n*3 + 0], xv1 = x[n*3 + 1], xv2 = x[n*3 + 2];
    float d0 = 0.f, d1 = 0.f, d2 = 0.f;
    #pragma unroll
    for (int kk = 0; kk < NRULES; ++kk) {
        float pot = ws[WOFF_TAIL + kk] * x[c0v[kk]];   // tail slots all index cell 0
        #pragma unroll
        for (int qq = 0; qq < NQ; ++qq)
            pot += ws[WOFF_POT + (kk * NQ + qq) * NCELLS + n];
        float u = pot - mv[kk];
        float sk = sv[kk];
        float field = __expf(-u*u / (2.f * sk * sk) - 0.001f) * 2.f - 1.f;
        float add = hv[kk] * field;
        int c = c1v[kk];   // wave-uniform
        if (c == 0) d0 += add; else if (c == 1) d1 += add; else d2 += add;
    }
    float* ox = out + 2 * NCELLS;
    ox[n*3 + 0] = fminf(fmaxf(xv0 + d0 * 0.1f, 0.f), 1.f);
    ox[n*3 + 1] = fminf(fmaxf(xv1 + d1 * 0.1f, 0.f), 1.f);
    ox[n*3 + 2] = fminf(fmaxf(xv2 + d2 * 0.1f, 0.f), 1.f);
}

extern "C" void kernel_launch(void* const* d_in, const int* in_sizes, int n_in,
                              void* d_out, int out_size, void* d_ws, size_t ws_size,
                              hipStream_t stream) {
    const float* pos = (const float*)d_in[0];
    const float* x   = (const float*)d_in[1];
    const int*   c0  = (const int*)  d_in[2];
    const int*   c1  = (const int*)  d_in[3];
    const float* r   = (const float*)d_in[4];
    const float* rk  = (const float*)d_in[5];
    const float* b   = (const float*)d_in[6];
    const float* w   = (const float*)d_in[7];
    const float* h   = (const float*)d_in[8];
    const float* m   = (const float*)d_in[9];
    const float* s   = (const float*)d_in[10];
    float* out = (float*)d_out;
    float* ws  = (float*)d_ws;

    // ABLATION ROUND: conv is idempotent (pure function of inputs); replay it
    // 9x inside the graph to isolate its per-invocation cost:
    //   c = (dur_us - 23.6) / 8   (R5 baseline: 1x conv + 1x update = 23.6us)
    // Output remains bit-identical to a single conv pass.
    #pragma unroll
    for (int rep = 0; rep < 9; ++rep)
        lenia_conv<<<CONV_BLOCKS, 256, 0, stream>>>(x, c0, r, rk, b, w, ws);
    lenia_update<<<NCELLS/64, 64, 0, stream>>>(pos, x, c0, c1, h, m, s, ws, out);
}

// Round 7
// 22.979 us; speedup vs baseline: 5.9219x; 5.9219x over previous
//
#include <hip/hip_runtime.h>
#include <math.h>

#define G 128
#define NCELLS (G*G)            // 16384
#define RAD 20
#define NS 41
#define NTAPS (NS*NS)           // 1681
#define NB_FULL 1850.0f         // 1 + (2R+3)^2 entries in the mean
#define NTAIL 168.0f            // (2R+3)^2 - (2R+1)^2
#define NRULES 4
#define NQ 16                   // stencil-row slices
#define QROWPAD 44
#define QBLK 144                // per-block stencil scratch stride (floats, 16B-aligned)
#define NTILES 16               // 8-row tiles
#define CONV_BLOCKS (NTILES*NRULES*NQ)   // 1024

// ws layout (float offsets)
#define WOFF_TAIL 0                                 // 4 floats (pad to 16)
#define WOFF_POT  16                                // 64 * NCELLS partial potentials
#define WOFF_BW   (WOFF_POT + NRULES*NQ*NCELLS)     // 1024 * 144 per-block stencil slices

__device__ __forceinline__ float kw(float d, float irk,
                                    float rk0, float rk1, float rk2,
                                    float b0, float b1, float b2,
                                    float iw0, float iw1, float iw2) {
    float em = 1.f / (1.f + __expf((d - 1.f) * 10.f));
    float dd = d * irk;
    float u0 = (dd - rk0) * iw0;
    float u1 = (dd - rk1) * iw1;
    float u2 = (dd - rk2) * iw2;
    return em * (b0 * __expf(-0.5f * u0 * u0)
               + b1 * __expf(-0.5f * u1 * u1)
               + b2 * __expf(-0.5f * u2 * u2));
}

// taps t=4q..4q+3 (stencil chunk rq) against window chunks wq, wq1.
// Per-accumulator FMA order is ascending t: identical to R5's summation order.
#define CROW(rq, wq, wq1)                                                         \
    a0 = fmaf(rq.x, wq.x,  a0); a1 = fmaf(rq.x, wq.y,  a1);                       \
    a2 = fmaf(rq.x, wq.z,  a2); a3 = fmaf(rq.x, wq.w,  a3);                       \
    a0 = fmaf(rq.y, wq.y,  a0); a1 = fmaf(rq.y, wq.z,  a1);                       \
    a2 = fmaf(rq.y, wq.w,  a2); a3 = fmaf(rq.y, wq1.x, a3);                       \
    a0 = fmaf(rq.z, wq.z,  a0); a1 = fmaf(rq.z, wq.w,  a1);                       \
    a2 = fmaf(rq.z, wq1.x, a2); a3 = fmaf(rq.z, wq1.y, a3);                       \
    a0 = fmaf(rq.w, wq.w,  a0); a1 = fmaf(rq.w, wq1.x, a1);                       \
    a2 = fmaf(rq.w, wq1.y, a2); a3 = fmaf(rq.w, wq1.z, a3);

// 1024 blocks: (16 eight-row tiles) x (4 rules) x (16 stencil-row slices).
// 256 threads = 8 rows x 32 lanes; 4 adjacent cells per thread.
__global__ __launch_bounds__(256, 4)
void lenia_conv(const float* __restrict__ x,
                const int* __restrict__ c0v,
                const float* __restrict__ rr,
                const float* __restrict__ rkv,
                const float* __restrict__ bv,
                const float* __restrict__ wv,
                float* __restrict__ ws) {
    __shared__ __align__(16) float xt[10*168];   // <= 10 halo'd rows
    __shared__ float red[4];

    const int bid  = blockIdx.x;
    const int q    = bid & 15;
    const int k    = (bid >> 4) & 3;
    const int tile = bid >> 6;                   // 0..15
    const int i0   = tile * 8;
    const int t    = threadIdx.x;
    // slices: nine rows-of-3 then seven rows-of-2 (9*3 + 7*2 = 41)
    const int nsi  = (q < 9) ? 3 : 2;
    const int si0  = (q < 9) ? 3*q : 27 + 2*(q - 9);
    const int r0   = i0 - RAD + si0;
    const int NR   = nsi + 7;                    // staged rows (<=10)
    const int ck   = c0v[k];                     // wave-uniform

    // ---- stage halo'd channel tile straight from interleaved x ----
    for (int idx = t; idx < NR * 168; idx += 256) {
        int rrow = idx / 168;
        int cc   = idx - rrow * 168;
        int grow = (r0 + rrow) & (G - 1);
        int gcol = (cc - 20) & (G - 1);
        xt[rrow*168 + cc] = x[grow*(G*3) + gcol*3 + ck];
    }

    // ---- per-block stencil recompute (proven exact since R3) ----
    const float irk = 1.f / rr[k];
    const float rk0 = rkv[k*3+0], rk1 = rkv[k*3+1], rk2 = rkv[k*3+2];
    const float b0  = bv[k*3+0],  b1  = bv[k*3+1],  b2  = bv[k*3+2];
    const float iw0 = 1.f / wv[k*3+0], iw1 = 1.f / wv[k*3+1], iw2 = 1.f / wv[k*3+2];
    const float invR = 1.f / (float)RAD;

    float vals[7];
    float lsum = 0.f;
    #pragma unroll
    for (int j = 0; j < 7; ++j) {
        int sidx = t + j * 256;
        float wk = 0.f;
        if (sidx < NTAPS) {
            int si = sidx / NS - RAD;
            int sj = sidx % NS - RAD;
            float d = sqrtf((float)(si*si + sj*sj)) * invR;
            wk = kw(d, irk, rk0, rk1, rk2, b0, b1, b2, iw0, iw1, iw2);
        }
        vals[j] = wk;
        lsum += wk;
    }
    #pragma unroll
    for (int mm = 32; mm > 0; mm >>= 1) lsum += __shfl_xor(lsum, mm, 64);
    if ((t & 63) == 0) red[t >> 6] = lsum;
    __syncthreads();                              // red ready AND xt staged
    const float S4 = red[0] + red[1] + red[2] + red[3];
    const float wself = kw(0.f, irk, rk0, rk1, rk2, b0, b1, b2, iw0, iw1, iw2);
    const float dtail = sqrtf(8192.f) * invR;
    const float wtail = kw(dtail, irk, rk0, rk1, rk2, b0, b1, b2, iw0, iw1, iw2);
    const float S = S4 + wself + NTAIL * wtail;
    const float inv = 1.f / (S * NB_FULL);

    // write this block's stencil slice to private global scratch (L2-hot on readback)
    float* bw = ws + WOFF_BW + bid * QBLK;
    const int lo = si0 * NS, hi = (si0 + nsi) * NS;
    #pragma unroll
    for (int j = 0; j < 7; ++j) {
        int sidx = t + j * 256;
        if (sidx >= lo && sidx < hi) {
            float v = vals[j] * inv;
            if (sidx == RAD*NS + RAD) v += wself * inv;   // fold self slot into (0,0)
            int l = sidx - lo;
            bw[(l / NS) * QROWPAD + (l % NS)] = v;
        }
    }
    if (t < 9) bw[(t / 3) * QROWPAD + NS + (t % 3)] = 0.f;   // zero pad cols rows 0..2
    if (tile == 0 && q == 0 && t == 0) ws[WOFF_TAIL + k] = NTAIL * wtail * inv;
    __syncthreads();                              // drains vmcnt: bw visible block-wide

    // ---- conv: 8 rows x 32 lanes, 4 adjacent cells per thread ----
    // Named float4 chunks: all 11 ds_read_b128 + 11 uniform global loads issue
    // up-front per row; compiler inserts partial lgkmcnt waits (no serial chain).
    const int row = t >> 5;
    const int cb  = (t & 31) * 4;
    float a0 = 0.f, a1 = 0.f, a2 = 0.f, a3 = 0.f;

    #pragma unroll
    for (int ii = 0; ii < 3; ++ii) {
        if (ii < nsi) {
            const float4* wp  = (const float4*)&xt[(row + ii)*168 + cb];  // LDS, 16B-aligned
            const float4* rp4 = (const float4*)(bw + ii * QROWPAD);       // global, wave-uniform
            float4 w0 = wp[0], w1 = wp[1], w2 = wp[2], w3 = wp[3], w4 = wp[4], w5 = wp[5];
            float4 w6 = wp[6], w7 = wp[7], w8 = wp[8], w9 = wp[9], w10 = wp[10];
            float4 r0 = rp4[0], r1 = rp4[1], r2 = rp4[2], r3 = rp4[3], r4 = rp4[4], r5 = rp4[5];
            float4 r6 = rp4[6], r7 = rp4[7], r8 = rp4[8], r9 = rp4[9], r10 = rp4[10];
            CROW(r0, w0, w1)  CROW(r1, w1, w2)  CROW(r2, w2, w3)  CROW(r3, w3, w4)
            CROW(r4, w4, w5)  CROW(r5, w5, w6)  CROW(r6, w6, w7)  CROW(r7, w7, w8)
            CROW(r8, w8, w9)  CROW(r9, w9, w10)
            a0 = fmaf(r10.x, w10.x, a0);
            a1 = fmaf(r10.x, w10.y, a1);
            a2 = fmaf(r10.x, w10.z, a2);
            a3 = fmaf(r10.x, w10.w, a3);
        }
    }

    int cell = (i0 + row) * G + cb;
    float4 res; res.x = a0; res.y = a1; res.z = a2; res.w = a3;
    *(float4*)&ws[WOFF_POT + (k * NQ + q) * NCELLS + cell] = res;
}

// 128 blocks x 128 threads (2 waves/block over 128 CUs): sum 64 partials,
// growth, delta, clip, pos pass-through.
__global__ __launch_bounds__(128)
void lenia_update(const float* __restrict__ pos,
                  const float* __restrict__ x,
                  const int* __restrict__ c0v,
                  const int* __restrict__ c1v,
                  const float* __restrict__ hv,
                  const float* __restrict__ mv,
                  const float* __restrict__ sv,
                  const float* __restrict__ ws,
                  float* __restrict__ out) {
    int n = blockIdx.x * 128 + threadIdx.x;
    *(float2*)&out[2*n] = *(const float2*)&pos[2*n];

    float xv0 = x[n*3 + 0], xv1 = x[n*3 + 1], xv2 = x[n*3 + 2];
    float d0 = 0.f, d1 = 0.f, d2 = 0.f;
    #pragma unroll
    for (int kk = 0; kk < NRULES; ++kk) {
        float pot = ws[WOFF_TAIL + kk] * x[c0v[kk]];   // tail slots all index cell 0
        #pragma unroll
        for (int qq = 0; qq < NQ; ++qq)
            pot += ws[WOFF_POT + (kk * NQ + qq) * NCELLS + n];
        float u = pot - mv[kk];
        float sk = sv[kk];
        float field = __expf(-u*u / (2.f * sk * sk) - 0.001f) * 2.f - 1.f;
        float add = hv[kk] * field;
        int c = c1v[kk];   // wave-uniform
        if (c == 0) d0 += add; else if (c == 1) d1 += add; else d2 += add;
    }
    float* ox = out + 2 * NCELLS;
    ox[n*3 + 0] = fminf(fmaxf(xv0 + d0 * 0.1f, 0.f), 1.f);
    ox[n*3 + 1] = fminf(fmaxf(xv1 + d1 * 0.1f, 0.f), 1.f);
    ox[n*3 + 2] = fminf(fmaxf(xv2 + d2 * 0.1f, 0.f), 1.f);
}

extern "C" void kernel_launch(void* const* d_in, const int* in_sizes, int n_in,
                              void* d_out, int out_size, void* d_ws, size_t ws_size,
                              hipStream_t stream) {
    const float* pos = (const float*)d_in[0];
    const float* x   = (const float*)d_in[1];
    const int*   c0  = (const int*)  d_in[2];
    const int*   c1  = (const int*)  d_in[3];
    const float* r   = (const float*)d_in[4];
    const float* rk  = (const float*)d_in[5];
    const float* b   = (const float*)d_in[6];
    const float* w   = (const float*)d_in[7];
    const float* h   = (const float*)d_in[8];
    const float* m   = (const float*)d_in[9];
    const float* s   = (const float*)d_in[10];
    float* out = (float*)d_out;
    float* ws  = (float*)d_ws;

    lenia_conv<<<CONV_BLOCKS, 256, 0, stream>>>(x, c0, r, rk, b, w, ws);
    lenia_update<<<NCELLS/128, 128, 0, stream>>>(pos, x, c0, c1, h, m, s, ws, out);
}